// Round 3
// baseline (1938.687 us; speedup 1.0000x reference)
//
#include <hip/hip_runtime.h>

#define NB 50            // bins
#define DD 512           // feature dim
#define KSZ 5
#define CHUNK 2048       // rows per chunk
#define NW 4             // waves per block
#define UNR 8            // rows-pairs in flight per wave

typedef float f4 __attribute__((ext_vector_type(4)));

// ---------------------------------------------------------------------------
// Fused streaming pass: one block = (2048-row chunk) x (128-col slice).
// features read ONCE, perfectly sequentially. Sum/sq accumulate into a
// bank-conflict-free LDS table via ds_add_f32:
//   lane l32, vec elem j holds data col c = 4*l32+j, stored at c' = l32+32*j
//   -> wave-wide ds_add addresses are stride-1 (conflict-free).
// Export de-permutes, so `part` holds natural column order.
// part layout: [chunk][slice][stat(2)][NB][128]
// ---------------------------------------------------------------------------
__global__ __launch_bounds__(256) void fds_main(
    const float* __restrict__ features,
    const int*   __restrict__ labels,
    float*       __restrict__ part,
    float*       __restrict__ g_cnt)
{
    __shared__ float s_acc[2 * NB * 128];   // 51.2 KB
    __shared__ int   s_lab[CHUNK];          // 8 KB
    __shared__ int   s_hist[NB];

    const int tid   = threadIdx.x;
    const int chunk = blockIdx.x >> 2;
    const int slice = blockIdx.x & 3;
    const int row0  = chunk * CHUNK;

    for (int i = tid; i < CHUNK; i += 256) s_lab[i] = labels[row0 + i];
    for (int i = tid; i < 2 * NB * 128; i += 256) s_acc[i] = 0.f;
    if (slice == 0 && tid < NB) s_hist[tid] = 0;
    __syncthreads();

    // per-chunk histogram (only one slice-block per chunk does it)
    if (slice == 0) {
        for (int i = tid; i < CHUNK; i += 256)
            __hip_atomic_fetch_add(&s_hist[s_lab[i]], 1,
                                   __ATOMIC_RELAXED, __HIP_MEMORY_SCOPE_WORKGROUP);
    }

    const int w    = tid >> 6;
    const int l    = tid & 63;
    const int half = l >> 5;          // which of the 2 rows this half-wave owns
    const int l32  = l & 31;
    const f4* __restrict__ fp =
        (const f4*)features + (size_t)slice * 32 + l32;   // col base (f4 units)

    // row-pair rp in [0, 1024); wave w owns rp = w, w+4, ...; row = 2*rp + half
    for (int k0 = 0; k0 < CHUNK / 2 / NW; k0 += UNR) {
        f4  v[UNR];
        int lb[UNR];
#pragma unroll
        for (int u = 0; u < UNR; ++u) {
            const int rp  = (k0 + u) * NW + w;
            const int row = 2 * rp + half;
            v[u]  = __builtin_nontemporal_load(fp + (size_t)row * (DD / 4));
            lb[u] = s_lab[row];                 // broadcast within half-wave
        }
#pragma unroll
        for (int u = 0; u < UNR; ++u) {
            float* as = &s_acc[lb[u] * 128];
            float* aq = as + NB * 128;
#pragma unroll
            for (int j = 0; j < 4; ++j) {
                const int cp = l32 + 32 * j;    // permuted col: stride-1/lane
                __hip_atomic_fetch_add(&as[cp], v[u][j],
                                       __ATOMIC_RELAXED, __HIP_MEMORY_SCOPE_WORKGROUP);
                __hip_atomic_fetch_add(&aq[cp], v[u][j] * v[u][j],
                                       __ATOMIC_RELAXED, __HIP_MEMORY_SCOPE_WORKGROUP);
            }
        }
    }
    __syncthreads();

    if (slice == 0 && tid < NB)
        __hip_atomic_fetch_add(&g_cnt[tid], (float)s_hist[tid],
                               __ATOMIC_RELAXED, __HIP_MEMORY_SCOPE_AGENT);

    // export partials, de-permuting columns back to natural order
    float* dst = part + (size_t)blockIdx.x * (2 * NB * 128);
    for (int i = tid; i < 2 * NB * 128; i += 256) {
        const int stat = i / (NB * 128);
        const int rem  = i - stat * (NB * 128);
        const int lab  = rem >> 7;
        const int c    = rem & 127;
        const int cp   = ((c & 3) << 5) | (c >> 2);
        dst[i] = s_acc[stat * (NB * 128) + lab * 128 + cp];
    }
}

// ---------------------------------------------------------------------------
// Fold the per-chunk partials into dense g_sum / g_sq (fully coalesced).
// ---------------------------------------------------------------------------
__global__ __launch_bounds__(256) void fds_partsum(
    const float* __restrict__ part, int nchunk,
    float* __restrict__ g_sum, float* __restrict__ g_sq)
{
    const int idx   = blockIdx.x * 256 + threadIdx.x;   // 0..25599
    const int lab   = idx >> 9;
    const int d     = idx & 511;
    const int slice = d >> 7;
    const int c     = d & 127;
    const size_t base = (size_t)slice * (2 * NB * 128) + lab * 128 + c;

    float s = 0.f, q = 0.f;
#pragma unroll 4
    for (int ch = 0; ch < nchunk; ++ch) {
        const float* p = part + (size_t)ch * 4 * (2 * NB * 128) + base;
        s += p[0];
        q += p[NB * 128];
    }
    g_sum[idx] = s;
    g_sq [idx] = q;
}

// ---------------------------------------------------------------------------
// Finalize (unchanged — verified correct).
// out layout: new_mean[25600] | new_var[25600] | new_num[50]
//             | smoothed_mean[25600] | smoothed_var[25600]
// ---------------------------------------------------------------------------
__global__ __launch_bounds__(256) void fds_finalize(
    const float* __restrict__ g_sum, const float* __restrict__ g_sq,
    const float* __restrict__ g_cnt,
    const float* __restrict__ running_mean, const float* __restrict__ running_var,
    const float* __restrict__ num_tracked, const float* __restrict__ kwin,
    float* __restrict__ out)
{
    __shared__ float s_cnt[NB];
    __shared__ float s_w[KSZ];
    const int tid = threadIdx.x;
    if (tid < NB)  s_cnt[tid] = g_cnt[tid];
    if (tid < KSZ) s_w[tid]   = kwin[tid];
    __syncthreads();

    const int idx = blockIdx.x * 256 + tid;   // 0..25599 (grid exactly 100)
    const int b = idx / DD;
    const int d = idx - b * DD;

    float sm = 0.f, sv = 0.f, my_nm = 0.f, my_nv = 0.f;
#pragma unroll
    for (int k = 0; k < KSZ; ++k) {
        const int i = b + k;
        const int bb = (i < 2) ? (2 - i) : ((i >= NB + 2) ? (2 * NB - i) : (i - 2));
        const float cnt    = s_cnt[bb];
        const float safe_n = fmaxf(cnt, 1.f);
        const float s   = g_sum[bb * DD + d];
        const float sqv = g_sq [bb * DD + d];
        const float mean = s / safe_n;
        const float var  = (sqv - safe_n * mean * mean) / fmaxf(cnt - 1.f, 1.f);
        const float rm = running_mean[bb * DD + d];
        const float rv = running_var [bb * DD + d];
        float nm, nv;
        if (cnt > 0.f) {
            nm = 0.1f * mean + 0.9f * rm;
            nv = 0.1f * var  + 0.9f * rv;
        } else {
            nm = rm; nv = rv;
        }
        sm += s_w[k] * nm;
        sv += s_w[k] * nv;
        if (k == 2) { my_nm = nm; my_nv = nv; }
    }
    out[idx]                    = my_nm;
    out[NB * DD + idx]          = my_nv;
    out[2 * NB * DD + NB + idx] = sm;
    out[3 * NB * DD + NB + idx] = sv;
    if (idx < NB)
        out[2 * NB * DD + idx] = num_tracked[idx] + s_cnt[idx];
}

extern "C" void kernel_launch(void* const* d_in, const int* in_sizes, int n_in,
                              void* d_out, int out_size, void* d_ws, size_t ws_size,
                              hipStream_t stream)
{
    const float* features     = (const float*)d_in[0];
    const int*   labels       = (const int*)  d_in[1];
    const float* running_mean = (const float*)d_in[2];
    const float* running_var  = (const float*)d_in[3];
    const float* num_tracked  = (const float*)d_in[4];
    const float* kwin         = (const float*)d_in[5];
    float* out = (float*)d_out;

    const int N      = in_sizes[1];     // 262144 rows
    const int nchunk = N / CHUNK;       // 128

    // ws layout: g_sum[25600] | g_sq[25600] | g_cnt[64 pad] | part (16B-aligned)
    float* g_sum = (float*)d_ws;
    float* g_sq  = g_sum + NB * DD;
    float* g_cnt = g_sq  + NB * DD;
    float* part  = g_cnt + 64;          // 51264 floats -> 205056 B, 16B-aligned

    hipMemsetAsync(g_cnt, 0, NB * sizeof(float), stream);

    fds_main<<<nchunk * 4, 256, 0, stream>>>(features, labels, part, g_cnt);

    fds_partsum<<<NB * DD / 256, 256, 0, stream>>>(part, nchunk, g_sum, g_sq);

    fds_finalize<<<NB * DD / 256, 256, 0, stream>>>(
        g_sum, g_sq, g_cnt, running_mean, running_var, num_tracked, kwin, out);
}

// Round 4
// 689.181 us; speedup vs baseline: 2.8130x; 2.8130x over previous
//
#include <hip/hip_runtime.h>

#define NB 50          // bins
#define DD 512         // feature dim
#define KSZ 5
#define SORT_ROWS 4096     // rows per sort block
#define EPT 16             // elements per thread in sort (4096/256)
#define UNR 8              // reduce inner unroll

typedef float f4 __attribute__((ext_vector_type(4)));

// ---------------------------------------------------------------------------
// Pass 0: block-local counting sort of labels. Each block owns 4096 rows and
// writes packed (row<<6)|lab entries, grouped by bin, into its own segment of
// `packed`. Exports the per-block bin start offsets (bofs, NB+1 entries per
// block); counts are later derived from bofs diffs (no global atomics).
// ---------------------------------------------------------------------------
__global__ __launch_bounds__(256) void fds_sort(
    const int* __restrict__ labels,
    int*       __restrict__ packed,   // [N]
    int*       __restrict__ bofs)     // [nblk][NB+1]
{
    __shared__ int s_hist[NB];
    __shared__ int s_cur[NB];
    const int tid  = threadIdx.x;
    const int base = blockIdx.x * SORT_ROWS;

    if (tid < NB) s_hist[tid] = 0;
    __syncthreads();

    int lab[EPT];
#pragma unroll
    for (int j = 0; j < EPT; ++j) {
        lab[j] = labels[base + j * 256 + tid];          // coalesced
        __hip_atomic_fetch_add(&s_hist[lab[j]], 1,
                               __ATOMIC_RELAXED, __HIP_MEMORY_SCOPE_WORKGROUP);
    }
    __syncthreads();

    if (tid == 0) {
        int run = 0;
        for (int b = 0; b < NB; ++b) { s_cur[b] = run; run += s_hist[b]; }
    }
    __syncthreads();

    // export per-block segment offsets BEFORE the placement loop mutates s_cur
    if (tid < NB) bofs[blockIdx.x * (NB + 1) + tid] = s_cur[tid];
    if (tid == 0) bofs[blockIdx.x * (NB + 1) + NB] = SORT_ROWS;
    __syncthreads();   // offsets saved before any s_cur mutation

#pragma unroll
    for (int j = 0; j < EPT; ++j) {
        const int l   = lab[j];
        const int pos = __hip_atomic_fetch_add(&s_cur[l], 1,
                              __ATOMIC_RELAXED, __HIP_MEMORY_SCOPE_WORKGROUP);
        const int row = base + j * 256 + tid;
        packed[base + pos] = (row << 6) | l;
    }
}

// ---------------------------------------------------------------------------
// Pass 1: ATOMIC-FREE segmented reduce (verified, ~90 us = ~93% of HBM
// achievable BW). One wave owns one (sort-block, bin, column-half): it
// accumulates exactly the rows of that bin segment (offsets from bofs) and
// writes its partial sums with plain float4 stores into an exclusively-owned
// slot of `part`. part layout: sum[nseg][DD] | sq[nseg][DD], nseg = nblk*NB.
// ---------------------------------------------------------------------------
__global__ __launch_bounds__(256) void fds_reduce(
    const float* __restrict__ features,
    const int*   __restrict__ packed,
    const int*   __restrict__ bofs,
    float*       __restrict__ part,
    int nseg)
{
    const int tid  = threadIdx.x;
    const int wave = tid >> 6;
    const int lane = tid & 63;
    const int gw   = blockIdx.x * 4 + wave;     // 0 .. nseg*2-1
    const int half = gw & 1;                    // column half
    const int seg  = gw >> 1;                   // 0 .. nseg-1
    const int blk  = seg / NB;
    const int bin  = seg - blk * NB;
    const int base = blk * SORT_ROWS;
    const int s    = bofs[blk * (NB + 1) + bin];
    const int e    = bofs[blk * (NB + 1) + bin + 1];
    const int c    = half * 64 + lane;          // f4 index within a row
    const f4* __restrict__ fp = (const f4*)features;   // DD/4 = 128 per row

    f4 sum = (f4)0.f, sq = (f4)0.f;
    for (int i0 = s; i0 < e; i0 += UNR) {
        const int n = e - i0;                   // >= 1, wave-uniform
        int pk[UNR];
#pragma unroll
        for (int j = 0; j < UNR; ++j)
            pk[j] = packed[base + i0 + (j < n ? j : 0)];   // clamped tail
        f4 v[UNR];
#pragma unroll
        for (int j = 0; j < UNR; ++j)
            v[j] = __builtin_nontemporal_load(
                fp + (size_t)(pk[j] >> 6) * (DD / 4) + c);
#pragma unroll
        for (int j = 0; j < UNR; ++j)
            if (j < n) { sum += v[j]; sq += v[j] * v[j]; }
    }

    f4* ps = (f4*)part;
    ps[(size_t)seg * (DD / 4) + c]          = sum;   // exclusive slot: no atomic
    ps[(size_t)(nseg + seg) * (DD / 4) + c] = sq;
}

// ---------------------------------------------------------------------------
// Pass 1.5: sum the nblk per-block partials into dense g_sum / g_sq.
// 25600 threads, fully coalesced; ~13 MB of L2/L3 traffic.
// ---------------------------------------------------------------------------
__global__ __launch_bounds__(256) void fds_partsum(
    const float* __restrict__ part, int nblk,
    float* __restrict__ g_sum, float* __restrict__ g_sq)
{
    const int idx = blockIdx.x * 256 + threadIdx.x;   // 0..25599
    const int bin = idx / DD;
    const int d   = idx - bin * DD;
    const int nseg = nblk * NB;
    float s = 0.f, q = 0.f;
#pragma unroll 4
    for (int blk = 0; blk < nblk; ++blk) {
        s += part[(size_t)(blk * NB + bin) * DD + d];
        q += part[(size_t)(nseg + blk * NB + bin) * DD + d];
    }
    g_sum[idx] = s;
    g_sq [idx] = q;
}

// ---------------------------------------------------------------------------
// Pass 2: finalize. Counts are derived from bofs diffs (exact integers in
// f32), removing the need for the g_cnt buffer, its memset, and the sort's
// agent-scope atomics. Math otherwise identical to the verified version.
// out layout: new_mean[25600] | new_var[25600] | new_num[50]
//             | smoothed_mean[25600] | smoothed_var[25600]
// ---------------------------------------------------------------------------
__global__ __launch_bounds__(256) void fds_finalize(
    const float* __restrict__ g_sum, const float* __restrict__ g_sq,
    const int*   __restrict__ bofs, int nblk,
    const float* __restrict__ running_mean, const float* __restrict__ running_var,
    const float* __restrict__ num_tracked, const float* __restrict__ kwin,
    float* __restrict__ out)
{
    __shared__ float s_cnt[NB];
    __shared__ float s_w[KSZ];
    const int tid = threadIdx.x;
    if (tid < NB) {
        int acc = 0;
        for (int blk = 0; blk < nblk; ++blk) {
            const int* bo = bofs + blk * (NB + 1);
            acc += bo[tid + 1] - bo[tid];
        }
        s_cnt[tid] = (float)acc;
    }
    if (tid < KSZ) s_w[tid] = kwin[tid];
    __syncthreads();

    const int idx = blockIdx.x * 256 + tid;   // 0..25599 (grid exactly 100)
    const int b = idx / DD;
    const int d = idx - b * DD;

    float sm = 0.f, sv = 0.f, my_nm = 0.f, my_nv = 0.f;
#pragma unroll
    for (int k = 0; k < KSZ; ++k) {
        const int i = b + k;
        const int bb = (i < 2) ? (2 - i) : ((i >= NB + 2) ? (2 * NB - i) : (i - 2));
        const float cnt    = s_cnt[bb];
        const float safe_n = fmaxf(cnt, 1.f);
        const float s   = g_sum[bb * DD + d];
        const float sqv = g_sq [bb * DD + d];
        const float mean = s / safe_n;
        const float var  = (sqv - safe_n * mean * mean) / fmaxf(cnt - 1.f, 1.f);
        const float rm = running_mean[bb * DD + d];
        const float rv = running_var [bb * DD + d];
        float nm, nv;
        if (cnt > 0.f) {
            nm = 0.1f * mean + 0.9f * rm;
            nv = 0.1f * var  + 0.9f * rv;
        } else {
            nm = rm; nv = rv;
        }
        sm += s_w[k] * nm;
        sv += s_w[k] * nv;
        if (k == 2) { my_nm = nm; my_nv = nv; }
    }
    out[idx]                    = my_nm;
    out[NB * DD + idx]          = my_nv;
    out[2 * NB * DD + NB + idx] = sm;
    out[3 * NB * DD + NB + idx] = sv;
    if (idx < NB)
        out[2 * NB * DD + idx] = num_tracked[idx] + s_cnt[idx];
}

extern "C" void kernel_launch(void* const* d_in, const int* in_sizes, int n_in,
                              void* d_out, int out_size, void* d_ws, size_t ws_size,
                              hipStream_t stream)
{
    const float* features     = (const float*)d_in[0];
    const int*   labels       = (const int*)  d_in[1];
    const float* running_mean = (const float*)d_in[2];
    const float* running_var  = (const float*)d_in[3];
    const float* num_tracked  = (const float*)d_in[4];
    const float* kwin         = (const float*)d_in[5];
    float* out = (float*)d_out;

    const int N    = in_sizes[1];        // 262144 rows
    const int nblk = N / SORT_ROWS;      // 64
    const int nseg = nblk * NB;          // 3200

    // ws layout: g_sum[25600] | g_sq[25600] | packed[N] | bofs[nblk*(NB+1)]
    //            | (16B-aligned) part[2*nseg*DD]
    // Everything is fully overwritten every launch: no memset needed.
    float* g_sum  = (float*)d_ws;
    float* g_sq   = g_sum + NB * DD;
    int*   packed = (int*)(g_sq + NB * DD);
    int*   bofs   = packed + N;
    size_t off    = ((size_t)((char*)(bofs + nblk * (NB + 1)) - (char*)d_ws) + 15)
                    & ~(size_t)15;
    float* part   = (float*)((char*)d_ws + off);

    fds_sort<<<nblk, 256, 0, stream>>>(labels, packed, bofs);

    // one wave per (sort-block, bin, column-half): nseg*2 waves, 4 per block
    fds_reduce<<<nseg * 2 / 4, 256, 0, stream>>>(features, packed, bofs, part, nseg);

    fds_partsum<<<NB * DD / 256, 256, 0, stream>>>(part, nblk, g_sum, g_sq);

    fds_finalize<<<NB * DD / 256, 256, 0, stream>>>(
        g_sum, g_sq, bofs, nblk, running_mean, running_var, num_tracked, kwin, out);
}